// Round 10
// baseline (501.702 us; speedup 1.0000x reference)
//
#include <hip/hip_runtime.h>
#include <hip/hip_bf16.h>
#include <cmath>

#define HH 512
#define WW 512
#define NIMG 12
#define RES (HH*WW)
#define NBINS 256
#define PXG 256             // pixels per block (= per wave, all 3 waves same pixels)

typedef __attribute__((ext_vector_type(8))) short bf8;     // 8 bf16 (4 VGPR) MFMA A/B frag
typedef __attribute__((ext_vector_type(4))) float f32x4;   // MFMA C/D frag

__device__ __forceinline__ unsigned bf_rne(float x) {      // f32 -> bf16 bits (setup/edge path)
    unsigned u = __float_as_uint(x);
    return (u + 0x7fffu + ((u >> 16) & 1u)) >> 16;
}
__device__ __forceinline__ float lk(float a) { return fmaxf(a, 0.01f * a); }  // leaky relu

__device__ __forceinline__ unsigned pk2(float a, float b) { // packed f32x2 -> bf16x2
    float2 t; t.x = a; t.y = b;
    union { __hip_bfloat162 h; unsigned u; } c;
    c.h = __float22bfloat162_rn(t);
    return c.u;
}

union bf8u { bf8 f; unsigned u[4]; };

// C/D frag pair -> next layer's B frag WITH leaky-relu applied on VALU
// (valid because producing layer's rows are sigma-permuted)
__device__ __forceinline__ bf8 actfrag(const f32x4 a0, const f32x4 a1) {
    bf8u r;
    r.u[0] = pk2(lk(a0[0]), lk(a0[1]));
    r.u[1] = pk2(lk(a0[2]), lk(a0[3]));
    r.u[2] = pk2(lk(a1[0]), lk(a1[1]));
    r.u[3] = pk2(lk(a1[2]), lk(a1[3]));
    return r.f;
}

// edge-tile patch builder with full bounds checks (rare path)
__device__ __forceinline__ bf8 slow_build(const float* __restrict__ X,
                                          int i, int jb, int m16, int q)
{
    const int jc = jb + m16;
    bf8 pf;
    #pragma unroll
    for (int j = 0; j < 8; ++j) {
        const int k = 8*q + j;
        float v = 0.0f;
        if (k < 21) {
            const int rr = i - 3 + k/7;
            const int cc = jc - 3 + k%7;
            if (rr >= 0 && cc >= 0 && cc < WW) v = X[rr*WW + cc];
        } else if (k < 24) {
            const int cc = jc - 3 + (k - 21);
            if (cc >= 0) v = X[i*WW + cc];
        } else if (k == 24) {
            v = 1.0f;
        }
        pf[j] = (short)bf_rne(v);
    }
    return pf;
}

#define MFMA(A, B, C) __builtin_amdgcn_mfma_f32_16x16x32_bf16((A), (B), (C), 0, 0, 0)

// full MLP for one predictor on one 16-px tile; activation on VALU (unfused):
// 7 MFMAs per tile, weight set stays single-copy (28 VGPR).
__device__ __forceinline__ void run_pred_tile(
    const bf8 w0a, const bf8 w0b,
    const bf8 w1a, const bf8 w1b,
    const bf8 w2a, const bf8 w2b,
    const bf8 w3f,
    const f32x4 c10, const f32x4 c11, const f32x4 c20, const f32x4 c21,
    const bf8 pf, f32x4& acc3)
{
    const f32x4 z = {0.f, 0.f, 0.f, 0.f};
    f32x4 za = MFMA(w0a, pf, z);
    f32x4 zb = MFMA(w0b, pf, z);
    bf8 h = actfrag(za, zb);
    za = MFMA(w1a, h, c10);
    zb = MFMA(w1b, h, c11);
    h = actfrag(za, zb);
    za = MFMA(w2a, h, c20);
    zb = MFMA(w2b, h, c21);
    h = actfrag(za, zb);
    acc3 = MFMA(w3f, h, acc3);
}

__global__ __launch_bounds__(192, 3) void codec_main(
    const float* __restrict__ x,
    const float* __restrict__ a_wT, const float* __restrict__ a_bT, const float* __restrict__ a_wL,
    const float* __restrict__ a_w1, const float* __restrict__ a_b1,
    const float* __restrict__ a_w2, const float* __restrict__ a_b2,
    const float* __restrict__ a_w3, const float* __restrict__ a_b3,
    const float* __restrict__ b_wT, const float* __restrict__ b_bT, const float* __restrict__ b_wL,
    const float* __restrict__ b_w1, const float* __restrict__ b_b1,
    const float* __restrict__ b_w2, const float* __restrict__ b_b2,
    const float* __restrict__ b_w3, const float* __restrict__ b_b3,
    const float* __restrict__ c_wT, const float* __restrict__ c_bT, const float* __restrict__ c_wL,
    const float* __restrict__ c_w1, const float* __restrict__ c_b1,
    const float* __restrict__ c_w2, const float* __restrict__ c_b2,
    const float* __restrict__ c_w3, const float* __restrict__ c_b3,
    float* __restrict__ sums,
    unsigned* __restrict__ hist_x,
    unsigned* __restrict__ hist_d)
{
    __shared__ float predbuf[3][PXG];
    __shared__ unsigned shx[NBINS], shd[NBINS];
    __shared__ float red[8];

    const int tid  = threadIdx.x;
    const int lane = tid & 63;
    const int wv   = tid >> 6;      // wave index == predictor index
    const int q    = lane >> 4;     // quad group: k = 8q+j (A/B), rows 4q+r (C/D)
    const int m16  = lane & 15;     // m (A) / n=pixel (B, C/D)

    for (int k = tid; k < NBINS; k += 192) { shx[k] = 0u; shd[k] = 0u; }

    const float* wTp[3] = {a_wT, b_wT, c_wT};
    const float* bTp[3] = {a_bT, b_bT, c_bT};
    const float* wLp[3] = {a_wL, b_wL, c_wL};
    const float* w1p[3] = {a_w1, b_w1, c_w1};
    const float* b1p[3] = {a_b1, b_b1, c_b1};
    const float* w2p[3] = {a_w2, b_w2, c_w2};
    const float* b2p[3] = {a_b2, b_b2, c_b2};
    const float* w3p[3] = {a_w3, b_w3, c_w3};
    const float* b3p[3] = {a_b3, b_b3, c_b3};

    // wave-uniform predictor index as an SGPR so weight loads stay scalar
    const int p = __builtin_amdgcn_readfirstlane(wv);
    const float* wT = wTp[p]; const float* bT = bTp[p]; const float* wL = wLp[p];
    const float* w1 = w1p[p]; const float* b1 = b1p[p];
    const float* w2 = w2p[p]; const float* b2 = b2p[p];
    const float* w3 = w3p[p]; const float* b3 = b3p[p];

    // ---- one-time: this predictor's weights -> MFMA A-frags (sigma rows) ----
    bf8 wA0[2], wA1[2], wA2[2];
    bf8 aw3;
    f32x4 c10, c11, c20, c21;
    #pragma unroll
    for (int mt = 0; mt < 2; ++mt) {
        const int ch = ((m16 >> 2) << 3) + (mt << 2) + (m16 & 3);   // sigma(16mt+m16)
        bf8 f0;
        #pragma unroll
        for (int j = 0; j < 8; ++j) {
            const int k = 8*q + j;
            float v = 0.0f;
            if (k < 21)       v = wT[ch*21 + k];
            else if (k < 24)  v = wL[ch*3 + (k - 21)];
            else if (k == 24) v = bT[ch];
            f0[j] = (short)bf_rne(v);
        }
        wA0[mt] = f0;
        {
            const f32x4 lo = *(const f32x4*)&w1[ch*32 + 8*q];
            const f32x4 hi = *(const f32x4*)&w1[ch*32 + 8*q + 4];
            bf8 g;
            #pragma unroll
            for (int j = 0; j < 4; ++j) { g[j] = (short)bf_rne(lo[j]); g[4+j] = (short)bf_rne(hi[j]); }
            wA1[mt] = g;
        }
        {
            const f32x4 lo = *(const f32x4*)&w2[ch*32 + 8*q];
            const f32x4 hi = *(const f32x4*)&w2[ch*32 + 8*q + 4];
            bf8 g;
            #pragma unroll
            for (int j = 0; j < 4; ++j) { g[j] = (short)bf_rne(lo[j]); g[4+j] = (short)bf_rne(hi[j]); }
            wA2[mt] = g;
        }
        // biases at computed row 16mt+4q+r -> logical sigma(...) = 8q+4mt+r
        if (mt == 0) { c10 = *(const f32x4*)&b1[8*q]; c20 = *(const f32x4*)&b2[8*q]; }
        else         { c11 = *(const f32x4*)&b1[8*q + 4]; c21 = *(const f32x4*)&b2[8*q + 4]; }
    }
    // L3 A-frag: w3 in row 0 only (columns natural: sigma fixed-point)
    {
        bf8 g;
        #pragma unroll
        for (int j = 0; j < 8; ++j) {
            const float v = (m16 == 0) ? w3[8*q + j] : 0.0f;
            g[j] = (short)bf_rne(v);
        }
        aw3 = g;
    }
    f32x4 bias3v = {0.f, 0.f, 0.f, 0.f};
    if (q == 0) bias3v[0] = b3[0];

    const int img = blockIdx.y;
    const float* __restrict__ X = x + (size_t)img * RES;
    const int wbase = blockIdx.x * PXG;       // all 3 waves share this pixel group
    const int i   = wbase >> 9;               // uniform row
    const int jb0 = wbase & (WW - 1);         // 0 or 256

    int koff[8];
    #pragma unroll
    for (int j = 0; j < 8; ++j) {
        const int k = 8*q + j;
        int row, col;
        if (k < 21)      { row = i - 3 + k/7; col = jb0 + m16 - 3 + k%7; }
        else if (k < 24) { row = i;           col = jb0 + m16 - 3 + (k - 21); }
        else             { row = i;           col = jb0 + m16; }
        koff[j] = (row*WW + col) * 4;
    }
    const bool rowsafe = (i >= 3);

    #pragma unroll 1
    for (int u = 0; u < 8; ++u) {
        const int t0 = 2*u, t1 = 2*u + 1;
        bf8 pf0, pf1;
        const bool fast = rowsafe && (jb0 + 16*t0 >= 3) && (jb0 + 16*t1 <= 493);
        if (fast) {
            bf8u r0, r1;
            if (q < 3) {
                float f0[8], f1[8];
                #pragma unroll
                for (int j = 0; j < 8; ++j) {
                    f0[j] = *(const float*)((const char*)X + koff[j]);
                    f1[j] = *(const float*)((const char*)X + koff[j] + 64);
                }
                r0.u[0] = pk2(f0[0], f0[1]); r0.u[1] = pk2(f0[2], f0[3]);
                r0.u[2] = pk2(f0[4], f0[5]); r0.u[3] = pk2(f0[6], f0[7]);
                r1.u[0] = pk2(f1[0], f1[1]); r1.u[1] = pk2(f1[2], f1[3]);
                r1.u[2] = pk2(f1[4], f1[5]); r1.u[3] = pk2(f1[6], f1[7]);
            } else {
                r0.u[0] = 0x00003f80u; r0.u[1] = 0u; r0.u[2] = 0u; r0.u[3] = 0u;
                r1.u[0] = 0x00003f80u; r1.u[1] = 0u; r1.u[2] = 0u; r1.u[3] = 0u;
            }
            pf0 = r0.f; pf1 = r1.f;
        } else {
            pf0 = slow_build(X, i, jb0 + 16*t0, m16, q);
            pf1 = slow_build(X, i, jb0 + 16*t1, m16, q);
        }

        f32x4 acc30 = bias3v;
        f32x4 acc31 = bias3v;
        run_pred_tile(wA0[0], wA0[1], wA1[0], wA1[1], wA2[0], wA2[1], aw3,
                      c10, c11, c20, c21, pf0, acc30);
        run_pred_tile(wA0[0], wA0[1], wA1[0], wA1[1], wA2[0], wA2[1], aw3,
                      c10, c11, c20, c21, pf1, acc31);

        if (q == 0) {
            predbuf[wv][t0*16 + m16] = fminf(fmaxf(acc30[0], -1.0f), 1.0f);
            predbuf[wv][t1*16 + m16] = fminf(fmaxf(acc31[0], -1.0f), 1.0f);
        }

        #pragma unroll
        for (int j = 0; j < 8; ++j) koff[j] += 128;
    }

    __syncthreads();

    // ---- stats: median, residual, histograms, sums (block-wide) ----
    float sx = 0.0f, sd = 0.0f;
    #pragma unroll 1
    for (int px = tid; px < PXG; px += 192) {
        const float xv = X[wbase + px];
        const float pa = predbuf[0][px];
        const float pb = predbuf[1][px];
        const float pc = predbuf[2][px];
        const float med = fmaxf(fminf(pa, fmaxf(pb, pc)), fminf(pb, pc));
        const float delta = fmodf(xv - med + 1.0f, 2.0f) - 1.0f;
        int bx = (int)floorf((xv + 1.0f) * 128.0f);
        bx = bx < 0 ? 0 : (bx > 255 ? 255 : bx);
        if (xv >= -1.0f && xv <= 1.0f) atomicAdd(&shx[bx], 1u);
        int bd = (int)floorf((delta + 1.0f) * 128.0f);
        bd = bd < 0 ? 0 : (bd > 255 ? 255 : bd);
        if (delta >= -1.0f && delta <= 1.0f) atomicAdd(&shd[bd], 1u);
        sx += xv*xv; sd += delta*delta;
    }
    #pragma unroll
    for (int off = 32; off > 0; off >>= 1) {
        sx += __shfl_down(sx, off);
        sd += __shfl_down(sd, off);
    }
    if (lane == 0) { red[wv] = sx; red[4 + wv] = sd; }
    __syncthreads();
    if (tid == 0) {
        atomicAdd(&sums[0], red[0] + red[1] + red[2]);
        atomicAdd(&sums[1], red[4] + red[5] + red[6]);
    }
    for (int k = tid; k < NBINS; k += 192) {
        if (shx[k]) atomicAdd(&hist_x[img*NBINS + k], shx[k]);
        if (shd[k]) atomicAdd(&hist_d[img*NBINS + k], shd[k]);
    }
}

__global__ __launch_bounds__(256) void codec_final(
    const float* __restrict__ sums,
    const unsigned* __restrict__ hist_x,
    const unsigned* __restrict__ hist_d,
    float* __restrict__ out)
{
    __shared__ float red[16];
    const int tid = threadIdx.x;
    float ex = 0.0f, ed = 0.0f;
    const float inv_res = 1.0f / (float)RES;
    for (int k = tid; k < NIMG*NBINS; k += 256) {
        const unsigned hx = hist_x[k];
        const unsigned hd = hist_d[k];
        if (hx) { const float p = (float)hx * inv_res; ex -= p * log2f(p); }
        if (hd) { const float p = (float)hd * inv_res; ed -= p * log2f(p); }
    }
    #pragma unroll
    for (int off = 32; off > 0; off >>= 1) {
        ex += __shfl_down(ex, off);
        ed += __shfl_down(ed, off);
    }
    const int lane = tid & 63, wv = tid >> 6;
    if (lane == 0) { red[wv] = ex; red[8 + wv] = ed; }
    __syncthreads();
    if (tid == 0) {
        const float Ex = red[0] + red[1] + red[2] + red[3];
        const float Ed = red[8] + red[9] + red[10] + red[11];
        const float inv_n = 1.0f / (float)(NIMG * RES);
        out[0] = 255.0f * sqrtf(sums[1] * inv_n);   // loss1 (deltas)
        out[1] = 255.0f * sqrtf(sums[0] * inv_n);   // loss0 (x)
        out[2] = Ex / (8.0f * (float)NIMG);         // invCR0
        out[3] = Ed / (8.0f * (float)NIMG);         // invCR1
    }
}

extern "C" void kernel_launch(void* const* d_in, const int* in_sizes, int n_in,
                              void* d_out, int out_size, void* d_ws, size_t ws_size,
                              hipStream_t stream)
{
    const float* x = (const float*)d_in[0];
    const float* w[27];
    for (int k = 0; k < 27; ++k) w[k] = (const float*)d_in[1 + k];

    float*    sums   = (float*)d_ws;
    unsigned* hist_x = (unsigned*)((char*)d_ws + 16);
    unsigned* hist_d = hist_x + NIMG*NBINS;
    const size_t zbytes = 16 + (size_t)2*NIMG*NBINS*sizeof(unsigned);
    hipMemsetAsync(d_ws, 0, zbytes, stream);

    dim3 grid(RES/PXG, NIMG);
    codec_main<<<grid, dim3(192), 0, stream>>>(
        x,
        w[0],  w[1],  w[2],  w[3],  w[4],  w[5],  w[6],  w[7],  w[8],
        w[9],  w[10], w[11], w[12], w[13], w[14], w[15], w[16], w[17],
        w[18], w[19], w[20], w[21], w[22], w[23], w[24], w[25], w[26],
        sums, hist_x, hist_d);
    codec_final<<<1, dim3(256), 0, stream>>>(sums, hist_x, hist_d, (float*)d_out);
}

// Round 12
// 378.046 us; speedup vs baseline: 1.3271x; 1.3271x over previous
//
#include <hip/hip_runtime.h>
#include <hip/hip_bf16.h>
#include <cmath>

#define HH 512
#define WW 512
#define NIMG 12
#define RES (HH*WW)
#define NBINS 256
#define PXB 1024            // pixels per block (4 waves)
#define PXW 256             // pixels per wave = half an image row

typedef __attribute__((ext_vector_type(8))) short bf8;     // 8 bf16 (4 VGPR) MFMA A/B frag
typedef __attribute__((ext_vector_type(4))) float f32x4;   // MFMA C/D frag

__device__ __forceinline__ unsigned bf_rne(float x) {      // f32 -> bf16 bits (setup/edge path)
    unsigned u = __float_as_uint(x);
    return (u + 0x7fffu + ((u >> 16) & 1u)) >> 16;
}
__device__ __forceinline__ float lk(float a) { return fmaxf(a, 0.01f * a); }  // leaky relu

__device__ __forceinline__ unsigned pk2(float a, float b) { // packed f32x2 -> bf16x2
    float2 t; t.x = a; t.y = b;
    union { __hip_bfloat162 h; unsigned u; } c;
    c.h = __float22bfloat162_rn(t);
    return c.u;
}

union bf8u { bf8 f; unsigned u[4]; };

// C/D frag pair -> next layer's B frag WITH leaky-relu on VALU
// (valid because producing layer's rows are sigma-permuted)
__device__ __forceinline__ bf8 actfrag(const f32x4 a0, const f32x4 a1) {
    bf8u r;
    r.u[0] = pk2(lk(a0[0]), lk(a0[1]));
    r.u[1] = pk2(lk(a0[2]), lk(a0[3]));
    r.u[2] = pk2(lk(a1[0]), lk(a1[1]));
    r.u[3] = pk2(lk(a1[2]), lk(a1[3]));
    return r.f;
}

// edge-tile patch builder with full bounds checks (rare path)
__device__ __forceinline__ bf8 slow_build(const float* __restrict__ X,
                                          int i, int jb, int m16, int q)
{
    const int jc = jb + m16;
    bf8 pf;
    #pragma unroll
    for (int j = 0; j < 8; ++j) {
        const int k = 8*q + j;
        float v = 0.0f;
        if (k < 21) {
            const int rr = i - 3 + k/7;
            const int cc = jc - 3 + k%7;
            if (rr >= 0 && cc >= 0 && cc < WW) v = X[rr*WW + cc];
        } else if (k < 24) {
            const int cc = jc - 3 + (k - 21);
            if (cc >= 0) v = X[i*WW + cc];
        } else if (k == 24) {
            v = 1.0f;
        }
        pf[j] = (short)bf_rne(v);
    }
    return pf;
}

#define MFMA(A, B, C) __builtin_amdgcn_mfma_f32_16x16x32_bf16((A), (B), (C), 0, 0, 0)

// one predictor, one 16-px tile: 7 MFMAs, unfused VALU activation.
// L3 weights sit in row p of w3f; result accumulates into shared acc3.
__device__ __forceinline__ void run_pred_tile(
    const bf8 w0a, const bf8 w0b,
    const bf8 w1a, const bf8 w1b,
    const bf8 w2a, const bf8 w2b,
    const bf8 w3f,
    const f32x4 c10, const f32x4 c11, const f32x4 c20, const f32x4 c21,
    const bf8 pf, f32x4& acc3)
{
    const f32x4 z = {0.f, 0.f, 0.f, 0.f};
    f32x4 za = MFMA(w0a, pf, z);
    f32x4 zb = MFMA(w0b, pf, z);
    bf8 h = actfrag(za, zb);
    za = MFMA(w1a, h, c10);
    zb = MFMA(w1b, h, c11);
    h = actfrag(za, zb);
    za = MFMA(w2a, h, c20);
    zb = MFMA(w2b, h, c21);
    h = actfrag(za, zb);
    acc3 = MFMA(w3f, h, acc3);
}

// wave-uniform: can iteration u use the unchecked fast loader?
__device__ __forceinline__ bool fast_ok(bool rowsafe, int jb0, int u) {
    return rowsafe && (jb0 + 32*u >= 3) && (jb0 + 32*u + 16 <= 493);
}

__global__ __launch_bounds__(256, 2) void codec_main(
    const float* __restrict__ x,
    const float* __restrict__ a_wT, const float* __restrict__ a_bT, const float* __restrict__ a_wL,
    const float* __restrict__ a_w1, const float* __restrict__ a_b1,
    const float* __restrict__ a_w2, const float* __restrict__ a_b2,
    const float* __restrict__ a_w3, const float* __restrict__ a_b3,
    const float* __restrict__ b_wT, const float* __restrict__ b_bT, const float* __restrict__ b_wL,
    const float* __restrict__ b_w1, const float* __restrict__ b_b1,
    const float* __restrict__ b_w2, const float* __restrict__ b_b2,
    const float* __restrict__ b_w3, const float* __restrict__ b_b3,
    const float* __restrict__ c_wT, const float* __restrict__ c_bT, const float* __restrict__ c_wL,
    const float* __restrict__ c_w1, const float* __restrict__ c_b1,
    const float* __restrict__ c_w2, const float* __restrict__ c_b2,
    const float* __restrict__ c_w3, const float* __restrict__ c_b3,
    float* __restrict__ sums,
    unsigned* __restrict__ hist_x,
    unsigned* __restrict__ hist_d)
{
    __shared__ unsigned shx[NBINS], shd[NBINS];
    __shared__ float red[8];

    const int tid  = threadIdx.x;
    const int lane = tid & 63;
    const int wv   = tid >> 6;
    const int q    = lane >> 4;     // quad group: k = 8q+j (A/B), rows 4q+r (C/D)
    const int m16  = lane & 15;     // m (A) / n=pixel (B, C/D)

    shx[tid] = 0u; shd[tid] = 0u;

    const float* wTp[3] = {a_wT, b_wT, c_wT};
    const float* bTp[3] = {a_bT, b_bT, c_bT};
    const float* wLp[3] = {a_wL, b_wL, c_wL};
    const float* w1p[3] = {a_w1, b_w1, c_w1};
    const float* b1p[3] = {a_b1, b_b1, c_b1};
    const float* w2p[3] = {a_w2, b_w2, c_w2};
    const float* b2p[3] = {a_b2, b_b2, c_b2};
    const float* w3p[3] = {a_w3, b_w3, c_w3};
    const float* b3p[3] = {a_b3, b_b3, c_b3};

    // ---- one-time: weights -> MFMA A-frags (rows sigma-permuted) ----
    bf8 wA0[3][2], wA1[3][2], wA2[3][2];
    bf8 aw3[3];
    f32x4 cb1[3][2], cb2[3][2];    // f32 bias C-inits, registers (loaded once)
    #pragma unroll
    for (int p = 0; p < 3; ++p) {
        #pragma unroll
        for (int mt = 0; mt < 2; ++mt) {
            const int ch = ((m16 >> 2) << 3) + (mt << 2) + (m16 & 3);   // sigma(16mt+m16)
            bf8 f0;
            #pragma unroll
            for (int j = 0; j < 8; ++j) {
                const int k = 8*q + j;
                float v = 0.0f;
                if (k < 21)       v = wTp[p][ch*21 + k];
                else if (k < 24)  v = wLp[p][ch*3 + (k - 21)];
                else if (k == 24) v = bTp[p][ch];
                f0[j] = (short)bf_rne(v);
            }
            wA0[p][mt] = f0;
            {
                const f32x4 lo = *(const f32x4*)&w1p[p][ch*32 + 8*q];
                const f32x4 hi = *(const f32x4*)&w1p[p][ch*32 + 8*q + 4];
                bf8 g;
                #pragma unroll
                for (int j = 0; j < 4; ++j) { g[j] = (short)bf_rne(lo[j]); g[4+j] = (short)bf_rne(hi[j]); }
                wA1[p][mt] = g;
            }
            {
                const f32x4 lo = *(const f32x4*)&w2p[p][ch*32 + 8*q];
                const f32x4 hi = *(const f32x4*)&w2p[p][ch*32 + 8*q + 4];
                bf8 g;
                #pragma unroll
                for (int j = 0; j < 4; ++j) { g[j] = (short)bf_rne(lo[j]); g[4+j] = (short)bf_rne(hi[j]); }
                wA2[p][mt] = g;
            }
            // bias rows: computed row 16mt+4q+r -> logical sigma = 8q+4mt+r
            if (mt == 0) { cb1[p][0] = *(const f32x4*)&b1p[p][8*q];     cb2[p][0] = *(const f32x4*)&b2p[p][8*q]; }
            else         { cb1[p][1] = *(const f32x4*)&b1p[p][8*q + 4]; cb2[p][1] = *(const f32x4*)&b2p[p][8*q + 4]; }
        }
        // L3 A-frag: w3_p in row p only (columns natural: sigma fixed-point)
        {
            bf8 g;
            #pragma unroll
            for (int j = 0; j < 8; ++j) {
                const float v = (m16 == p) ? w3p[p][8*q + j] : 0.0f;
                g[j] = (short)bf_rne(v);
            }
            aw3[p] = g;
        }
    }
    // L3 bias C-init: row r (<3) = b3 of predictor r
    f32x4 bias3v = {0.f, 0.f, 0.f, 0.f};
    if (q == 0) { bias3v[0] = b3p[0][0]; bias3v[1] = b3p[1][0]; bias3v[2] = b3p[2][0]; }

    __syncthreads();

    const int img = blockIdx.y;
    const float* __restrict__ X = x + (size_t)img * RES;
    const char*  Xc = (const char*)X;
    const int wbase = blockIdx.x * PXB + wv * PXW;
    const int i   = wbase >> 9;          // wave-uniform row
    const int jb0 = wbase & (WW - 1);    // 0 or 256

    int koff[8];
    #pragma unroll
    for (int j = 0; j < 8; ++j) {
        const int k = 8*q + j;
        int row, col;
        if (k < 21)      { row = i - 3 + k/7; col = jb0 + m16 - 3 + k%7; }
        else if (k < 24) { row = i;           col = jb0 + m16 - 3 + (k - 21); }
        else             { row = i;           col = jb0 + m16; }
        koff[j] = (row*WW + col) * 4;
    }
    int xoff = (i*WW + jb0 + m16) * 4;
    const bool rowsafe = (i >= 3);

    // ---- software pipeline: prefetch u=0's patch (only if addresses valid) ----
    float nf0[8], nf1[8];
    float nxv0, nxv1;
    if (fast_ok(rowsafe, jb0, 0)) {
        #pragma unroll
        for (int j = 0; j < 8; ++j) {
            nf0[j] = *(const float*)(Xc + koff[j]);
            nf1[j] = *(const float*)(Xc + koff[j] + 64);
        }
    }
    nxv0 = *(const float*)(Xc + xoff);
    nxv1 = *(const float*)(Xc + xoff + 64);

    float sx = 0.0f, sd = 0.0f;

    #pragma unroll 1
    for (int u = 0; u < 8; ++u) {
        const bool fast = fast_ok(rowsafe, jb0, u);

        // consume prefetched values (prefetched iff fast)
        bf8 pf0, pf1;
        if (fast) {
            bf8u r0, r1;
            if (q < 3) {
                r0.u[0] = pk2(nf0[0], nf0[1]); r0.u[1] = pk2(nf0[2], nf0[3]);
                r0.u[2] = pk2(nf0[4], nf0[5]); r0.u[3] = pk2(nf0[6], nf0[7]);
                r1.u[0] = pk2(nf1[0], nf1[1]); r1.u[1] = pk2(nf1[2], nf1[3]);
                r1.u[2] = pk2(nf1[4], nf1[5]); r1.u[3] = pk2(nf1[6], nf1[7]);
            } else {
                r0.u[0] = 0x00003f80u; r0.u[1] = 0u; r0.u[2] = 0u; r0.u[3] = 0u;
                r1.u[0] = 0x00003f80u; r1.u[1] = 0u; r1.u[2] = 0u; r1.u[3] = 0u;
            }
            pf0 = r0.f; pf1 = r1.f;
        } else {
            pf0 = slow_build(X, i, jb0 + 32*u,      m16, q);
            pf1 = slow_build(X, i, jb0 + 32*u + 16, m16, q);
        }
        const float xv0 = nxv0, xv1 = nxv1;

        // issue next iteration's loads BEFORE the MFMA chains (latency hidden);
        // patch prefetch only when next iteration's addresses are in-bounds.
        if (u < 7) {
            if (fast_ok(rowsafe, jb0, u + 1)) {
                #pragma unroll
                for (int j = 0; j < 8; ++j) {
                    nf0[j] = *(const float*)(Xc + koff[j] + 128);
                    nf1[j] = *(const float*)(Xc + koff[j] + 192);
                }
            }
            nxv0 = *(const float*)(Xc + xoff + 128);
            nxv1 = *(const float*)(Xc + xoff + 192);
        }

        f32x4 acc30 = bias3v;     // all 3 preds land in rows 0..2
        f32x4 acc31 = bias3v;
        #pragma unroll
        for (int p = 0; p < 3; ++p) {
            run_pred_tile(wA0[p][0], wA0[p][1], wA1[p][0], wA1[p][1],
                          wA2[p][0], wA2[p][1], aw3[p],
                          cb1[p][0], cb1[p][1], cb2[p][0], cb2[p][1], pf0, acc30);
            run_pred_tile(wA0[p][0], wA0[p][1], wA1[p][0], wA1[p][1],
                          wA2[p][0], wA2[p][1], aw3[p],
                          cb1[p][0], cb1[p][1], cb2[p][0], cb2[p][1], pf1, acc31);
        }

        // inline stats at q==0: preds a,b,c in acc3 regs 0..2 for pixel m16
        if (q == 0) {
            {
                const float pa = fminf(fmaxf(acc30[0], -1.0f), 1.0f);
                const float pb = fminf(fmaxf(acc30[1], -1.0f), 1.0f);
                const float pc = fminf(fmaxf(acc30[2], -1.0f), 1.0f);
                const float med = fmaxf(fminf(pa, fmaxf(pb, pc)), fminf(pb, pc));
                const float delta = fmodf(xv0 - med + 1.0f, 2.0f) - 1.0f;
                int bx = (int)floorf((xv0 + 1.0f) * 128.0f);
                bx = bx < 0 ? 0 : (bx > 255 ? 255 : bx);
                if (xv0 >= -1.0f && xv0 <= 1.0f) atomicAdd(&shx[bx], 1u);
                int bd = (int)floorf((delta + 1.0f) * 128.0f);
                bd = bd < 0 ? 0 : (bd > 255 ? 255 : bd);
                if (delta >= -1.0f && delta <= 1.0f) atomicAdd(&shd[bd], 1u);
                sx += xv0*xv0; sd += delta*delta;
            }
            {
                const float pa = fminf(fmaxf(acc31[0], -1.0f), 1.0f);
                const float pb = fminf(fmaxf(acc31[1], -1.0f), 1.0f);
                const float pc = fminf(fmaxf(acc31[2], -1.0f), 1.0f);
                const float med = fmaxf(fminf(pa, fmaxf(pb, pc)), fminf(pb, pc));
                const float delta = fmodf(xv1 - med + 1.0f, 2.0f) - 1.0f;
                int bx = (int)floorf((xv1 + 1.0f) * 128.0f);
                bx = bx < 0 ? 0 : (bx > 255 ? 255 : bx);
                if (xv1 >= -1.0f && xv1 <= 1.0f) atomicAdd(&shx[bx], 1u);
                int bd = (int)floorf((delta + 1.0f) * 128.0f);
                bd = bd < 0 ? 0 : (bd > 255 ? 255 : bd);
                if (delta >= -1.0f && delta <= 1.0f) atomicAdd(&shd[bd], 1u);
                sx += xv1*xv1; sd += delta*delta;
            }
        }

        #pragma unroll
        for (int j = 0; j < 8; ++j) koff[j] += 128;
        xoff += 128;
    }

    // ---- block reduction ----
    #pragma unroll
    for (int off = 32; off > 0; off >>= 1) {
        sx += __shfl_down(sx, off);
        sd += __shfl_down(sd, off);
    }
    if (lane == 0) { red[wv] = sx; red[4 + wv] = sd; }
    __syncthreads();
    if (tid == 0) {
        atomicAdd(&sums[0], red[0] + red[1] + red[2] + red[3]);
        atomicAdd(&sums[1], red[4] + red[5] + red[6] + red[7]);
    }
    if (shx[tid]) atomicAdd(&hist_x[img*NBINS + tid], shx[tid]);
    if (shd[tid]) atomicAdd(&hist_d[img*NBINS + tid], shd[tid]);
}

__global__ __launch_bounds__(256) void codec_final(
    const float* __restrict__ sums,
    const unsigned* __restrict__ hist_x,
    const unsigned* __restrict__ hist_d,
    float* __restrict__ out)
{
    __shared__ float red[16];
    const int tid = threadIdx.x;
    float ex = 0.0f, ed = 0.0f;
    const float inv_res = 1.0f / (float)RES;
    for (int k = tid; k < NIMG*NBINS; k += 256) {
        const unsigned hx = hist_x[k];
        const unsigned hd = hist_d[k];
        if (hx) { const float p = (float)hx * inv_res; ex -= p * log2f(p); }
        if (hd) { const float p = (float)hd * inv_res; ed -= p * log2f(p); }
    }
    #pragma unroll
    for (int off = 32; off > 0; off >>= 1) {
        ex += __shfl_down(ex, off);
        ed += __shfl_down(ed, off);
    }
    const int lane = tid & 63, wv = tid >> 6;
    if (lane == 0) { red[wv] = ex; red[8 + wv] = ed; }
    __syncthreads();
    if (tid == 0) {
        const float Ex = red[0] + red[1] + red[2] + red[3];
        const float Ed = red[8] + red[9] + red[10] + red[11];
        const float inv_n = 1.0f / (float)(NIMG * RES);
        out[0] = 255.0f * sqrtf(sums[1] * inv_n);   // loss1 (deltas)
        out[1] = 255.0f * sqrtf(sums[0] * inv_n);   // loss0 (x)
        out[2] = Ex / (8.0f * (float)NIMG);         // invCR0
        out[3] = Ed / (8.0f * (float)NIMG);         // invCR1
    }
}

extern "C" void kernel_launch(void* const* d_in, const int* in_sizes, int n_in,
                              void* d_out, int out_size, void* d_ws, size_t ws_size,
                              hipStream_t stream)
{
    const float* x = (const float*)d_in[0];
    const float* w[27];
    for (int k = 0; k < 27; ++k) w[k] = (const float*)d_in[1 + k];

    float*    sums   = (float*)d_ws;
    unsigned* hist_x = (unsigned*)((char*)d_ws + 16);
    unsigned* hist_d = hist_x + NIMG*NBINS;
    const size_t zbytes = 16 + (size_t)2*NIMG*NBINS*sizeof(unsigned);
    hipMemsetAsync(d_ws, 0, zbytes, stream);

    dim3 grid(RES/PXB, NIMG);
    codec_main<<<grid, dim3(256), 0, stream>>>(
        x,
        w[0],  w[1],  w[2],  w[3],  w[4],  w[5],  w[6],  w[7],  w[8],
        w[9],  w[10], w[11], w[12], w[13], w[14], w[15], w[16], w[17],
        w[18], w[19], w[20], w[21], w[22], w[23], w[24], w[25], w[26],
        sums, hist_x, hist_d);
    codec_final<<<1, dim3(256), 0, stream>>>(sums, hist_x, hist_d, (float*)d_out);
}